// Round 10
// baseline (156.024 us; speedup 1.0000x reference)
//
#include <hip/hip_runtime.h>

// Problem constants
#define HW 4096           // H*W
#define CHW 262144        // C*H*W
#define OUT_ELEMS 4194304 // B*C*H*W
#define FLT_BIG 3.4e38f

typedef __attribute__((ext_vector_type(8))) short  short8;   // MFMA A/B frag (4 VGPR)
typedef __attribute__((ext_vector_type(4))) float  floatx4;  // MFMA C/D frag
typedef __attribute__((ext_vector_type(4))) int    intx4;

// ws layout (no zero-init needed -- every byte read is written first):
//   [4096,6144)     enorm f32[512]
//   [8192,139264)   planes_frag u16 (128 KB, fragment-major split-bf16 codebook)
//   [139264,147456) ws_sse double[1024]  (per-block SSE, plain stores)

__device__ __forceinline__ unsigned bf16_rne(float f) {
    unsigned u = __float_as_uint(f);
    return (u + 0x7FFFu + ((u >> 16) & 1u)) >> 16;  // RNE bf16 bits
}

__device__ __forceinline__ void split8(const float* f, intx4* hi, intx4* lo) {
    unsigned h[4], l[4];
#pragma unroll
    for (int j = 0; j < 4; ++j) {
        const unsigned h0 = bf16_rne(f[2 * j]);
        const unsigned h1 = bf16_rne(f[2 * j + 1]);
        const float hf0 = __uint_as_float(h0 << 16);
        const float hf1 = __uint_as_float(h1 << 16);
        const unsigned l0 = bf16_rne(f[2 * j] - hf0);
        const unsigned l1 = bf16_rne(f[2 * j + 1] - hf1);
        h[j] = h0 | (h1 << 16);
        l[j] = l0 | (l1 << 16);
    }
    *hi = intx4{(int)h[0], (int)h[1], (int)h[2], (int)h[3]};
    *lo = intx4{(int)l[0], (int)l[1], (int)l[2], (int)l[3]};
}

// prep: 16 blocks x 256 threads; 32 codes/block. Fragment-major split-bf16
// codebook + exact fp32 enorm. (Unchanged from R9.)
__global__ void vq_prep(const float* __restrict__ emb,
                        unsigned short* __restrict__ pfrag,
                        float* __restrict__ enorm) {
    const int t = threadIdx.x;
    const int lane = t & 63;
#pragma unroll
    for (int i = 0; i < 8; ++i) {
        const int f    = (i << 8) + t;
        const int code = (blockIdx.x << 5) + (f >> 6);  // wave-uniform
        const int c    = lane;
        const float v  = emb[(code << 6) + c];          // 256B coalesced
        const unsigned hb = bf16_rne(v);
        const float hf    = __uint_as_float(hb << 16);
        const unsigned lb = bf16_rne(v - hf);
        const int nc = code >> 6, grp = (code & 63) >> 4, n = code & 15;
        const int q = (c & 31) >> 3, o = c & 7;
        const int jh = c >> 5;        // eh element e=c
        const int jl = 2 + (c >> 5);  // el element e=64+c
        pfrag[((((size_t)(nc*4 + jh)*4 + grp)*4 + q)*16 + n)*8 + o] = (unsigned short)hb;
        pfrag[((((size_t)(nc*4 + jl)*4 + grp)*4 + q)*16 + n)*8 + o] = (unsigned short)lb;
        float s = v * v;
#pragma unroll
        for (int off = 32; off > 0; off >>= 1) s += __shfl_xor(s, off, 64);
        if (lane == 0) enorm[code] = s;
    }
}

// Main: 1024 blocks x 256 threads; 64 rows/block (one (b,h) stripe, row = w).
// K-loop = R9 (zero barriers, L2-direct fragment loads) + unroll 2 for
// cross-chunk load pipelining. R10: the serialized 1-wave conditional fp64
// rescue is replaced by an unconditional 4-wave-parallel exact verify of the
// approx top-2 (no gap threshold, no divergent branch).
__global__ __launch_bounds__(256)
void vq_main(const float* __restrict__ x_in, const float* __restrict__ emb,
             const unsigned short* __restrict__ pfrag,
             const float* __restrict__ enorm,
             float* __restrict__ out, float* __restrict__ idx_out,
             double* __restrict__ ws_sse) {
    __shared__ float  b1s[2][64], b2s[2][64];
    __shared__ int    i1s[2][64], i2s[2][64];
    __shared__ int    c1i[64], c2i[64], qidx[64];
    __shared__ double parts[4][64];
    __shared__ double ls_red[4];

    const int t     = threadIdx.x;
    const int lane  = t & 63;
    const int wv    = t >> 6;
    const int col   = lane & 15;
    const int quad  = lane >> 4;
    const int blk   = blockIdx.x;
    const int mrow0 = (wv >> 1) << 5;   // wave row base (0/32)
    const int khalf = wv & 1;           // code-half of each 64-chunk
    const int ncol0 = khalf << 5;
    const int b = blk >> 6, h = blk & 63;
    const float* xb = x_in + (size_t)b * CHW + h * 64;

    // ---- A-frags: direct from BCHW global, split-bf16, register-resident ----
    short8 Ah[2][2], Al[2][2];
#pragma unroll
    for (int m = 0; m < 2; ++m) {
        const int w = mrow0 + (m << 4) + col;
#pragma unroll
        for (int u = 0; u < 2; ++u) {
            float f[8];
#pragma unroll
            for (int j = 0; j < 8; ++j) {
                const int c = (u << 5) + (quad << 3) + j;
                f[j] = xb[(size_t)c * HW + w];
            }
            intx4 hi, lo;
            split8(f, &hi, &lo);
            Ah[m][u] = __builtin_bit_cast(short8, hi);
            Al[m][u] = __builtin_bit_cast(short8, lo);
        }
    }

    float B1[8], B2[8]; int I1[8], I2[8];
#pragma unroll
    for (int s = 0; s < 8; ++s) { B1[s] = FLT_BIG; B2[s] = FLT_BIG; I1[s] = 0x3FFFFFFF; I2[s] = 0x3FFFFFFF; }

    const char* pf = (const char*)pfrag + (size_t)lane * 16 + ((size_t)khalf << 11);

#pragma unroll 2
    for (int nc = 0; nc < 8; ++nc) {
        const char* base = pf + ((size_t)nc << 14);
        const int K0 = nc << 6;
        const float en0 = enorm[K0 + ncol0 + col];
        const float en1 = enorm[K0 + ncol0 + 16 + col];

        floatx4 a00{0.f,0.f,0.f,0.f}, a01{0.f,0.f,0.f,0.f};
        floatx4 a10{0.f,0.f,0.f,0.f}, a11{0.f,0.f,0.f,0.f};
#define BLD(j, g) (*(const short8*)(base + ((j) << 12) + ((g) << 10)))
        {   // j=0: eh c[0,32)
            const short8 b0 = BLD(0, 0), b1 = BLD(0, 1);
            a00 = __builtin_amdgcn_mfma_f32_16x16x32_bf16(Ah[0][0], b0, a00, 0, 0, 0);
            a01 = __builtin_amdgcn_mfma_f32_16x16x32_bf16(Ah[0][0], b1, a01, 0, 0, 0);
            a10 = __builtin_amdgcn_mfma_f32_16x16x32_bf16(Ah[1][0], b0, a10, 0, 0, 0);
            a11 = __builtin_amdgcn_mfma_f32_16x16x32_bf16(Ah[1][0], b1, a11, 0, 0, 0);
            a00 = __builtin_amdgcn_mfma_f32_16x16x32_bf16(Al[0][0], b0, a00, 0, 0, 0);
            a01 = __builtin_amdgcn_mfma_f32_16x16x32_bf16(Al[0][0], b1, a01, 0, 0, 0);
            a10 = __builtin_amdgcn_mfma_f32_16x16x32_bf16(Al[1][0], b0, a10, 0, 0, 0);
            a11 = __builtin_amdgcn_mfma_f32_16x16x32_bf16(Al[1][0], b1, a11, 0, 0, 0);
        }
        {   // j=1: eh c[32,64)
            const short8 b0 = BLD(1, 0), b1 = BLD(1, 1);
            a00 = __builtin_amdgcn_mfma_f32_16x16x32_bf16(Ah[0][1], b0, a00, 0, 0, 0);
            a01 = __builtin_amdgcn_mfma_f32_16x16x32_bf16(Ah[0][1], b1, a01, 0, 0, 0);
            a10 = __builtin_amdgcn_mfma_f32_16x16x32_bf16(Ah[1][1], b0, a10, 0, 0, 0);
            a11 = __builtin_amdgcn_mfma_f32_16x16x32_bf16(Ah[1][1], b1, a11, 0, 0, 0);
            a00 = __builtin_amdgcn_mfma_f32_16x16x32_bf16(Al[0][1], b0, a00, 0, 0, 0);
            a01 = __builtin_amdgcn_mfma_f32_16x16x32_bf16(Al[0][1], b1, a01, 0, 0, 0);
            a10 = __builtin_amdgcn_mfma_f32_16x16x32_bf16(Al[1][1], b0, a10, 0, 0, 0);
            a11 = __builtin_amdgcn_mfma_f32_16x16x32_bf16(Al[1][1], b1, a11, 0, 0, 0);
        }
        {   // j=2: el c[0,32)
            const short8 b0 = BLD(2, 0), b1 = BLD(2, 1);
            a00 = __builtin_amdgcn_mfma_f32_16x16x32_bf16(Ah[0][0], b0, a00, 0, 0, 0);
            a01 = __builtin_amdgcn_mfma_f32_16x16x32_bf16(Ah[0][0], b1, a01, 0, 0, 0);
            a10 = __builtin_amdgcn_mfma_f32_16x16x32_bf16(Ah[1][0], b0, a10, 0, 0, 0);
            a11 = __builtin_amdgcn_mfma_f32_16x16x32_bf16(Ah[1][0], b1, a11, 0, 0, 0);
        }
        {   // j=3: el c[32,64)
            const short8 b0 = BLD(3, 0), b1 = BLD(3, 1);
            a00 = __builtin_amdgcn_mfma_f32_16x16x32_bf16(Ah[0][1], b0, a00, 0, 0, 0);
            a01 = __builtin_amdgcn_mfma_f32_16x16x32_bf16(Ah[0][1], b1, a01, 0, 0, 0);
            a10 = __builtin_amdgcn_mfma_f32_16x16x32_bf16(Ah[1][1], b0, a10, 0, 0, 0);
            a11 = __builtin_amdgcn_mfma_f32_16x16x32_bf16(Ah[1][1], b1, a11, 0, 0, 0);
        }
#undef BLD

#pragma unroll
        for (int nt = 0; nt < 2; ++nt) {
            const int code = K0 + ncol0 + (nt << 4) + col;
            const float en = nt ? en1 : en0;
#pragma unroll
            for (int m = 0; m < 2; ++m) {
                const floatx4 av = nt ? (m ? a11 : a01) : (m ? a10 : a00);
#pragma unroll
                for (int reg = 0; reg < 4; ++reg) {
                    const float d = fmaf(-2.f, av[reg], en);
                    const int s = (m << 2) + reg;
                    if (d < B1[s])      { B2[s] = B1[s]; I2[s] = I1[s]; B1[s] = d; I1[s] = code; }
                    else if (d < B2[s]) { B2[s] = d; I2[s] = code; }
                }
            }
        }
    }

    // ---- cross-lane top-2 butterfly over col bits (disjoint code sets per
    // lane, explicit index tie-break = first-occurrence) ----
#pragma unroll
    for (int off = 1; off <= 8; off <<= 1) {
#pragma unroll
        for (int s = 0; s < 8; ++s) {
            const float ob1 = __shfl_xor(B1[s], off, 64);
            const int   oi1 = __shfl_xor(I1[s], off, 64);
            const float ob2 = __shfl_xor(B2[s], off, 64);
            const int   oi2 = __shfl_xor(I2[s], off, 64);
            if (ob1 < B1[s] || (ob1 == B1[s] && oi1 < I1[s])) {
                float nb2; int ni2;
                if (B1[s] < ob2 || (B1[s] == ob2 && I1[s] < oi2)) { nb2 = B1[s]; ni2 = I1[s]; }
                else                                              { nb2 = ob2;  ni2 = oi2; }
                B1[s] = ob1; I1[s] = oi1; B2[s] = nb2; I2[s] = ni2;
            } else if (ob1 < B2[s] || (ob1 == B2[s] && oi1 < I2[s])) {
                B2[s] = ob1; I2[s] = oi1;
            }
        }
    }
    if (col == 0) {
#pragma unroll
        for (int s = 0; s < 8; ++s) {
            const int row = mrow0 + ((s >> 2) << 4) + (quad << 2) + (s & 3);
            b1s[khalf][row] = B1[s]; b2s[khalf][row] = B2[s];
            i1s[khalf][row] = I1[s]; i2s[khalf][row] = I2[s];
        }
    }
    __syncthreads();

    // ---- merge halves -> approx top-2 candidates per row (no threshold) ----
    if (t < 64) {
        const int r = t;
        float b1 = b1s[0][r], b2 = b2s[0][r];
        int   i1 = i1s[0][r], i2 = i2s[0][r];
        const float c1 = b1s[1][r]; const int j1 = i1s[1][r];
        const float c2 = b2s[1][r]; const int j2 = i2s[1][r];
        if (c1 < b1 || (c1 == b1 && j1 < i1))      { b2 = b1; i2 = i1; b1 = c1; i1 = j1; }
        else if (c1 < b2 || (c1 == b2 && j1 < i2)) { b2 = c1; i2 = j1; }
        if (c2 < b2 || (c2 == b2 && j2 < i2))      { b2 = c2; i2 = j2; }
        c1i[r] = i1; c2i[r] = i2;
    }
    __syncthreads();

    // ---- unconditional 4-wave-parallel exact fp64 verify of both candidates:
    // wave k -> candidate (k&1), c-half (k>>1), 32 c's each. Branchless,
    // replaces the serialized 1-wave conditional rescue (R9's worst phase). ----
    {
        const int r  = t & 63;
        const int k  = t >> 6;
        const int ch = k >> 1;
        const int code = (k & 1) ? c2i[r] : c1i[r];
        const float* ep = emb + ((size_t)code << 6) + (ch << 5);
        const float* xq = xb + r;   // x[c*HW + r]: lanes r consecutive -> coalesced
        double d0 = 0.0, d1 = 0.0;
#pragma unroll
        for (int cc = 0; cc < 32; cc += 2) {
            const int c = (ch << 5) + cc;
            const double f0 = (double)xq[(size_t)c * HW]       - (double)ep[cc];
            const double f1 = (double)xq[(size_t)(c + 1) * HW] - (double)ep[cc + 1];
            d0 = fma(f0, f0, d0);
            d1 = fma(f1, f1, d1);
        }
        parts[k][r] = d0 + d1;
    }
    __syncthreads();
    if (t < 64) {
        const double d1 = parts[0][t] + parts[2][t];   // candidate 1 exact
        const double d2 = parts[1][t] + parts[3][t];   // candidate 2 exact
        int i1 = c1i[t];
        const int i2 = c2i[t];
        if (d2 < d1 || (d2 == d1 && i2 < i1)) i1 = i2; // lowest-index tie-break
        qidx[t] = i1;
        idx_out[(blk << 6) + t] = (float)i1;
    }
    __syncthreads();

    // ---- epilogue: quantized out (coalesced along w) + per-block SSE ----
    {
        const int r  = lane;
        const int c0 = wv << 4;
        const float* xp = xb + r;
        float*       op = out + (size_t)b * CHW + h * 64 + r;
        const float* eq = emb + ((size_t)qidx[r] << 6);
        float sse_local = 0.f;
#pragma unroll
        for (int cc = 0; cc < 16; ++cc) {
            const int c = c0 + cc;
            const float qc = eq[c];
            const float dx = qc - xp[(size_t)c * HW];
            sse_local = fmaf(dx, dx, sse_local);
            op[(size_t)c * HW] = qc;
        }
#pragma unroll
        for (int off = 32; off > 0; off >>= 1)
            sse_local += __shfl_down(sse_local, off, 64);
        if (lane == 0) ls_red[wv] = (double)sse_local;
        __syncthreads();
        if (t == 0)
            ws_sse[blk] = (ls_red[0] + ls_red[1]) + (ls_red[2] + ls_red[3]);  // plain store
    }
}

// tail: 1 block x 256 threads. Histogram (LDS atomics) from idx_out +
// perplexity + commitment + active codes. Kernel boundary = coherence.
__global__ void vq_tail(const float* __restrict__ idx_out,
                        const double* __restrict__ ws_sse,
                        const float* __restrict__ weight,
                        float* __restrict__ scal) {
    __shared__ unsigned hs[512];
    __shared__ double redt[4], reds[4];
    __shared__ int    redi[4];
    const int t = threadIdx.x;
    hs[t] = 0u; hs[t + 256] = 0u;
    __syncthreads();
    const float4* ip = (const float4*)idx_out;
#pragma unroll 4
    for (int i = 0; i < 64; ++i) {
        const float4 v = ip[t + (i << 8)];     // coalesced
        atomicAdd(&hs[(int)v.x], 1u);
        atomicAdd(&hs[(int)v.y], 1u);
        atomicAdd(&hs[(int)v.z], 1u);
        atomicAdd(&hs[(int)v.w], 1u);
    }
    __syncthreads();
    const int lane = t & 63, wv = t >> 6;
    double term = 0.0, ssep = 0.0; int act = 0;
#pragma unroll
    for (int j = 0; j < 2; ++j) {
        const int k = t + (j << 8);
        const double p = (double)hs[k] / 65536.0;
        term += p * log(p + 1e-10);
        act  += (weight[k] >= 0.01f) ? 1 : 0;
    }
#pragma unroll
    for (int j = 0; j < 4; ++j) ssep += ws_sse[t + (j << 8)];
#pragma unroll
    for (int off = 32; off > 0; off >>= 1) {
        term += __shfl_down(term, off, 64);
        ssep += __shfl_down(ssep, off, 64);
        act  += __shfl_down(act,  off, 64);
    }
    if (lane == 0) { redt[wv] = term; reds[wv] = ssep; redi[wv] = act; }
    __syncthreads();
    if (t == 0) {
        double s = 0.0, ss = 0.0; int a = 0;
#pragma unroll
        for (int i = 0; i < 4; ++i) { s += redt[i]; ss += reds[i]; a += redi[i]; }
        scal[0] = (float)(ss / 4194304.0);  // commitment_loss
        scal[1] = (float)exp(-s);           // perplexity
        scal[2] = (float)a;                 // active_codes
    }
}

extern "C" void kernel_launch(void* const* d_in, const int* in_sizes, int n_in,
                              void* d_out, int out_size, void* d_ws, size_t ws_size,
                              hipStream_t stream) {
    const float* x      = (const float*)d_in[0];  // [16,64,64,64] fp32
    const float* emb    = (const float*)d_in[1];  // [512,64] fp32
    const float* weight = (const float*)d_in[2];  // [512] fp32

    float* out = (float*)d_out;
    float*          enorm  = (float*)((char*)d_ws + 4096);
    unsigned short* pfrag  = (unsigned short*)((char*)d_ws + 8192);
    double*         ws_sse = (double*)((char*)d_ws + 139264);

    float* scal    = out + OUT_ELEMS;      // commitment, perplexity, active
    float* idx_out = out + OUT_ELEMS + 3;  // indices as float [65536]

    vq_prep<<<16, 256, 0, stream>>>(emb, pfrag, enorm);
    vq_main<<<1024, 256, 0, stream>>>(x, emb, pfrag, enorm, out, idx_out, ws_sse);
    vq_tail<<<1, 256, 0, stream>>>(idx_out, ws_sse, weight, scal);
}

// Round 11
// 121.809 us; speedup vs baseline: 1.2809x; 1.2809x over previous
//
#include <hip/hip_runtime.h>

// Problem constants
#define HW 4096           // H*W
#define CHW 262144        // C*H*W
#define OUT_ELEMS 4194304 // B*C*H*W
#define FLT_BIG 3.4e38f

typedef __attribute__((ext_vector_type(8))) short  short8;   // MFMA A/B frag (4 VGPR)
typedef __attribute__((ext_vector_type(4))) float  floatx4;  // MFMA C/D frag
typedef __attribute__((ext_vector_type(4))) int    intx4;

// ws layout (no zero-init needed -- every byte read is written first):
//   [0,2048)        enorm f32[512]
//   [4096,135168)   planes_frag u16 (128 KB, fragment-major split-bf16 codebook)
//   [135168,151552) ws_sse double[2048]  (per-block SSE, plain stores)
//   [151552,184320) part u32[16][512]    (per-hist-block partial histograms)

__device__ __forceinline__ unsigned bf16_rne(float f) {
    unsigned u = __float_as_uint(f);
    return (u + 0x7FFFu + ((u >> 16) & 1u)) >> 16;  // RNE bf16 bits
}

__device__ __forceinline__ void split8(const float* f, intx4* hi, intx4* lo) {
    unsigned h[4], l[4];
#pragma unroll
    for (int j = 0; j < 4; ++j) {
        const unsigned h0 = bf16_rne(f[2 * j]);
        const unsigned h1 = bf16_rne(f[2 * j + 1]);
        const float hf0 = __uint_as_float(h0 << 16);
        const float hf1 = __uint_as_float(h1 << 16);
        const unsigned l0 = bf16_rne(f[2 * j] - hf0);
        const unsigned l1 = bf16_rne(f[2 * j + 1] - hf1);
        h[j] = h0 | (h1 << 16);
        l[j] = l0 | (l1 << 16);
    }
    *hi = intx4{(int)h[0], (int)h[1], (int)h[2], (int)h[3]};
    *lo = intx4{(int)l[0], (int)l[1], (int)l[2], (int)l[3]};
}

// prep: 16 blocks x 256 threads; 32 codes/block. Fragment-major split-bf16
// codebook + exact fp32 enorm. (Unchanged since R9.)
__global__ void vq_prep(const float* __restrict__ emb,
                        unsigned short* __restrict__ pfrag,
                        float* __restrict__ enorm) {
    const int t = threadIdx.x;
    const int lane = t & 63;
#pragma unroll
    for (int i = 0; i < 8; ++i) {
        const int f    = (i << 8) + t;
        const int code = (blockIdx.x << 5) + (f >> 6);  // wave-uniform
        const int c    = lane;
        const float v  = emb[(code << 6) + c];          // 256B coalesced
        const unsigned hb = bf16_rne(v);
        const float hf    = __uint_as_float(hb << 16);
        const unsigned lb = bf16_rne(v - hf);
        const int nc = code >> 6, grp = (code & 63) >> 4, n = code & 15;
        const int q = (c & 31) >> 3, o = c & 7;
        const int jh = c >> 5;        // eh element e=c
        const int jl = 2 + (c >> 5);  // el element e=64+c
        pfrag[((((size_t)(nc*4 + jh)*4 + grp)*4 + q)*16 + n)*8 + o] = (unsigned short)hb;
        pfrag[((((size_t)(nc*4 + jl)*4 + grp)*4 + q)*16 + n)*8 + o] = (unsigned short)lb;
        float s = v * v;
#pragma unroll
        for (int off = 32; off > 0; off >>= 1) s += __shfl_xor(s, off, 64);
        if (lane == 0) enorm[code] = s;
    }
}

// Main: 2048 blocks x 256 threads; 32 rows/block (half a (b,h) stripe).
// Wave wv: 16-row M-tile (wv>>1), code-half (wv&1) of each 64-code chunk.
// R11: halved per-block serial chain + doubled block supply (8 blocks/CU)
// to fill the latency bubbles R10's counters exposed (occ 24%, VALU 69%,
// dur pinned at 72us across 3 structural variants). Phase algorithms are
// carried from R9/R10 unchanged, re-indexed for 32 rows.
__global__ __launch_bounds__(256)
void vq_main(const float* __restrict__ x_in, const float* __restrict__ emb,
             const unsigned short* __restrict__ pfrag,
             const float* __restrict__ enorm,
             float* __restrict__ out, float* __restrict__ idx_out,
             double* __restrict__ ws_sse) {
    __shared__ float  b1s[2][32], b2s[2][32];
    __shared__ int    i1s[2][32], i2s[2][32];
    __shared__ int    c1i[32], c2i[32], qidx[32];
    __shared__ double parts[8][32];
    __shared__ double ls_red[4];

    const int t     = threadIdx.x;
    const int lane  = t & 63;
    const int wv    = t >> 6;
    const int col   = lane & 15;
    const int quad  = lane >> 4;
    const int blk   = blockIdx.x;
    const int mrow0 = (wv >> 1) << 4;   // wave row base (0/16)
    const int khalf = wv & 1;           // code-half of each 64-chunk
    const int ncol0 = khalf << 5;
    const int half = blk & 1;           // which 32-w half of the stripe
    const int bh = blk >> 1;
    const int b = bh >> 6, h = bh & 63;
    const float* xb = x_in + (size_t)b * CHW + h * 64 + (half << 5);

    // ---- A-frags: one 16-row M-tile, direct from BCHW global (coalesced),
    // split-bf16, register-resident ----
    short8 Ah[2], Al[2];
#pragma unroll
    for (int u = 0; u < 2; ++u) {
        float f[8];
#pragma unroll
        for (int j = 0; j < 8; ++j) {
            const int c = (u << 5) + (quad << 3) + j;
            f[j] = xb[(size_t)c * HW + mrow0 + col];
        }
        intx4 hi, lo;
        split8(f, &hi, &lo);
        Ah[u] = __builtin_bit_cast(short8, hi);
        Al[u] = __builtin_bit_cast(short8, lo);
    }

    float B1[4], B2[4]; int I1[4], I2[4];
#pragma unroll
    for (int s = 0; s < 4; ++s) { B1[s] = FLT_BIG; B2[s] = FLT_BIG; I1[s] = 0x3FFFFFFF; I2[s] = 0x3FFFFFFF; }

    const char* pf = (const char*)pfrag + (size_t)lane * 16 + ((size_t)khalf << 11);

#pragma unroll 2
    for (int nc = 0; nc < 8; ++nc) {
        const char* base = pf + ((size_t)nc << 14);
        const int K0 = nc << 6;
        const float en0 = enorm[K0 + ncol0 + col];
        const float en1 = enorm[K0 + ncol0 + 16 + col];

        floatx4 a0{0.f,0.f,0.f,0.f}, a1{0.f,0.f,0.f,0.f};
#define BLD(j, g) (*(const short8*)(base + ((j) << 12) + ((g) << 10)))
        {   // j=0: eh c[0,32) -> Ah[0] + Al[0]
            const short8 b0 = BLD(0, 0), b1 = BLD(0, 1);
            a0 = __builtin_amdgcn_mfma_f32_16x16x32_bf16(Ah[0], b0, a0, 0, 0, 0);
            a1 = __builtin_amdgcn_mfma_f32_16x16x32_bf16(Ah[0], b1, a1, 0, 0, 0);
            a0 = __builtin_amdgcn_mfma_f32_16x16x32_bf16(Al[0], b0, a0, 0, 0, 0);
            a1 = __builtin_amdgcn_mfma_f32_16x16x32_bf16(Al[0], b1, a1, 0, 0, 0);
        }
        {   // j=1: eh c[32,64) -> Ah[1] + Al[1]
            const short8 b0 = BLD(1, 0), b1 = BLD(1, 1);
            a0 = __builtin_amdgcn_mfma_f32_16x16x32_bf16(Ah[1], b0, a0, 0, 0, 0);
            a1 = __builtin_amdgcn_mfma_f32_16x16x32_bf16(Ah[1], b1, a1, 0, 0, 0);
            a0 = __builtin_amdgcn_mfma_f32_16x16x32_bf16(Al[1], b0, a0, 0, 0, 0);
            a1 = __builtin_amdgcn_mfma_f32_16x16x32_bf16(Al[1], b1, a1, 0, 0, 0);
        }
        {   // j=2: el c[0,32) -> Ah[0] only
            const short8 b0 = BLD(2, 0), b1 = BLD(2, 1);
            a0 = __builtin_amdgcn_mfma_f32_16x16x32_bf16(Ah[0], b0, a0, 0, 0, 0);
            a1 = __builtin_amdgcn_mfma_f32_16x16x32_bf16(Ah[0], b1, a1, 0, 0, 0);
        }
        {   // j=3: el c[32,64) -> Ah[1] only
            const short8 b0 = BLD(3, 0), b1 = BLD(3, 1);
            a0 = __builtin_amdgcn_mfma_f32_16x16x32_bf16(Ah[1], b0, a0, 0, 0, 0);
            a1 = __builtin_amdgcn_mfma_f32_16x16x32_bf16(Ah[1], b1, a1, 0, 0, 0);
        }
#undef BLD

#pragma unroll
        for (int nt = 0; nt < 2; ++nt) {
            const int code = K0 + ncol0 + (nt << 4) + col;
            const float en = nt ? en1 : en0;
            const floatx4 av = nt ? a1 : a0;
#pragma unroll
            for (int reg = 0; reg < 4; ++reg) {
                const float d = fmaf(-2.f, av[reg], en);
                if (d < B1[reg])      { B2[reg] = B1[reg]; I2[reg] = I1[reg]; B1[reg] = d; I1[reg] = code; }
                else if (d < B2[reg]) { B2[reg] = d; I2[reg] = code; }
            }
        }
    }

    // ---- cross-lane top-2 butterfly over col bits (disjoint code sets per
    // lane, explicit index tie-break = first-occurrence) ----
#pragma unroll
    for (int off = 1; off <= 8; off <<= 1) {
#pragma unroll
        for (int s = 0; s < 4; ++s) {
            const float ob1 = __shfl_xor(B1[s], off, 64);
            const int   oi1 = __shfl_xor(I1[s], off, 64);
            const float ob2 = __shfl_xor(B2[s], off, 64);
            const int   oi2 = __shfl_xor(I2[s], off, 64);
            if (ob1 < B1[s] || (ob1 == B1[s] && oi1 < I1[s])) {
                float nb2; int ni2;
                if (B1[s] < ob2 || (B1[s] == ob2 && I1[s] < oi2)) { nb2 = B1[s]; ni2 = I1[s]; }
                else                                              { nb2 = ob2;  ni2 = oi2; }
                B1[s] = ob1; I1[s] = oi1; B2[s] = nb2; I2[s] = ni2;
            } else if (ob1 < B2[s] || (ob1 == B2[s] && oi1 < I2[s])) {
                B2[s] = ob1; I2[s] = oi1;
            }
        }
    }
    if (col == 0) {
#pragma unroll
        for (int s = 0; s < 4; ++s) {
            const int row = mrow0 + (quad << 2) + s;   // C/D: row = quad*4 + reg
            b1s[khalf][row] = B1[s]; b2s[khalf][row] = B2[s];
            i1s[khalf][row] = I1[s]; i2s[khalf][row] = I2[s];
        }
    }
    __syncthreads();

    // ---- merge halves -> approx top-2 candidates per row ----
    if (t < 32) {
        const int r = t;
        float b1 = b1s[0][r], b2 = b2s[0][r];
        int   i1 = i1s[0][r], i2 = i2s[0][r];
        const float c1 = b1s[1][r]; const int j1 = i1s[1][r];
        const float c2 = b2s[1][r]; const int j2 = i2s[1][r];
        if (c1 < b1 || (c1 == b1 && j1 < i1))      { b2 = b1; i2 = i1; b1 = c1; i1 = j1; }
        else if (c1 < b2 || (c1 == b2 && j1 < i2)) { b2 = c1; i2 = j1; }
        if (c2 < b2 || (c2 == b2 && j2 < i2))      { b2 = c2; i2 = j2; }
        c1i[r] = i1; c2i[r] = i2;
    }
    __syncthreads();

    // ---- unconditional 8-way-parallel exact fp64 verify of both candidates:
    // thread group k = t>>5 -> candidate (k&1), c-quarter (k>>1), 16 c each ----
    {
        const int r  = t & 31;
        const int k  = t >> 5;
        const int cq = k >> 1;
        const int code = (k & 1) ? c2i[r] : c1i[r];
        const float* ep = emb + ((size_t)code << 6) + (cq << 4);
        const float* xq = xb + r;   // lanes r consecutive -> coalesced
        double d0 = 0.0, d1 = 0.0;
#pragma unroll
        for (int cc = 0; cc < 16; cc += 2) {
            const int c = (cq << 4) + cc;
            const double f0 = (double)xq[(size_t)c * HW]       - (double)ep[cc];
            const double f1 = (double)xq[(size_t)(c + 1) * HW] - (double)ep[cc + 1];
            d0 = fma(f0, f0, d0);
            d1 = fma(f1, f1, d1);
        }
        parts[k][r] = d0 + d1;
    }
    __syncthreads();
    if (t < 32) {
        const double d1 = parts[0][t] + parts[2][t] + parts[4][t] + parts[6][t];
        const double d2 = parts[1][t] + parts[3][t] + parts[5][t] + parts[7][t];
        int i1 = c1i[t];
        const int i2 = c2i[t];
        if (d2 < d1 || (d2 == d1 && i2 < i1)) i1 = i2; // lowest-index tie-break
        qidx[t] = i1;
        idx_out[(blk << 5) + t] = (float)i1;
    }
    __syncthreads();

    // ---- epilogue: quantized out (coalesced along w) + per-block SSE ----
    {
        const int r  = t & 31;
        const int c0 = (t >> 5) << 3;    // 8 channels per thread-group
        const float* xp = xb + r;
        float*       op = out + (size_t)b * CHW + h * 64 + (half << 5) + r;
        const float* eq = emb + ((size_t)qidx[r] << 6);
        float sse_local = 0.f;
#pragma unroll
        for (int cc = 0; cc < 8; ++cc) {
            const int c = c0 + cc;
            const float qc = eq[c];
            const float dx = qc - xp[(size_t)c * HW];
            sse_local = fmaf(dx, dx, sse_local);
            op[(size_t)c * HW] = qc;
        }
#pragma unroll
        for (int off = 32; off > 0; off >>= 1)
            sse_local += __shfl_down(sse_local, off, 64);
        if (lane == 0) ls_red[wv] = (double)sse_local;
        __syncthreads();
        if (t == 0)
            ws_sse[blk] = (ls_red[0] + ls_red[1]) + (ls_red[2] + ls_red[3]);  // plain store
    }
}

// hist: 16 blocks x 256 threads; LDS histogram of 4096 indices each, plain
// partial-store. Kernel-boundary ordering provides coherence (R9-proven).
__global__ void vq_hist(const float* __restrict__ idx_out,
                        unsigned* __restrict__ part) {
    __shared__ unsigned hs[512];
    const int t = threadIdx.x;
    hs[t] = 0u; hs[t + 256] = 0u;
    __syncthreads();
    const float4* ip = (const float4*)(idx_out + (blockIdx.x << 12));
#pragma unroll
    for (int i = 0; i < 4; ++i) {
        const float4 v = ip[(i << 8) + t];    // coalesced
        atomicAdd(&hs[(int)v.x], 1u);         // LDS atomics
        atomicAdd(&hs[(int)v.y], 1u);
        atomicAdd(&hs[(int)v.z], 1u);
        atomicAdd(&hs[(int)v.w], 1u);
    }
    __syncthreads();
    unsigned* pp = part + (blockIdx.x << 9);
    pp[t] = hs[t]; pp[t + 256] = hs[t + 256];  // coalesced plain stores
}

// scal: 1 block x 512 threads. Partial hists -> perplexity; ws_sse ->
// commitment; weight -> active codes.
__global__ void vq_scal(const unsigned* __restrict__ part,
                        const double* __restrict__ ws_sse,
                        const float* __restrict__ weight,
                        float* __restrict__ scal) {
    __shared__ double redt[8], reds[8];
    __shared__ int    redi[8];
    const int k = threadIdx.x;       // 0..511 = code
    const int lane = k & 63, wv = k >> 6;
    unsigned cnt = 0;
#pragma unroll
    for (int p = 0; p < 16; ++p) cnt += part[(p << 9) + k];   // coalesced per p
    const double pr = (double)cnt / 65536.0;
    double term = pr * log(pr + 1e-10);
    double ssep = 0.0;
#pragma unroll
    for (int j = 0; j < 4; ++j) ssep += ws_sse[k + (j << 9)];
    int act = (weight[k] >= 0.01f) ? 1 : 0;
#pragma unroll
    for (int off = 32; off > 0; off >>= 1) {
        term += __shfl_down(term, off, 64);
        ssep += __shfl_down(ssep, off, 64);
        act  += __shfl_down(act,  off, 64);
    }
    if (lane == 0) { redt[wv] = term; reds[wv] = ssep; redi[wv] = act; }
    __syncthreads();
    if (k == 0) {
        double s = 0.0, ss = 0.0; int a = 0;
#pragma unroll
        for (int i = 0; i < 8; ++i) { s += redt[i]; ss += reds[i]; a += redi[i]; }
        scal[0] = (float)(ss / 4194304.0);  // commitment_loss
        scal[1] = (float)exp(-s);           // perplexity
        scal[2] = (float)a;                 // active_codes
    }
}

extern "C" void kernel_launch(void* const* d_in, const int* in_sizes, int n_in,
                              void* d_out, int out_size, void* d_ws, size_t ws_size,
                              hipStream_t stream) {
    const float* x      = (const float*)d_in[0];  // [16,64,64,64] fp32
    const float* emb    = (const float*)d_in[1];  // [512,64] fp32
    const float* weight = (const float*)d_in[2];  // [512] fp32

    float* out = (float*)d_out;
    float*          enorm  = (float*)d_ws;
    unsigned short* pfrag  = (unsigned short*)((char*)d_ws + 4096);
    double*         ws_sse = (double*)((char*)d_ws + 135168);
    unsigned*       part   = (unsigned*)((char*)d_ws + 151552);

    float* scal    = out + OUT_ELEMS;      // commitment, perplexity, active
    float* idx_out = out + OUT_ELEMS + 3;  // indices as float [65536]

    vq_prep<<<16, 256, 0, stream>>>(emb, pfrag, enorm);
    vq_main<<<2048, 256, 0, stream>>>(x, emb, pfrag, enorm, out, idx_out, ws_sse);
    vq_hist<<<16, 256, 0, stream>>>(idx_out, part);
    vq_scal<<<1, 512, 0, stream>>>(part, ws_sse, weight, scal);
}